// Round 2
// baseline (307.779 us; speedup 1.0000x reference)
//
#include <hip/hip_runtime.h>
#include <stdint.h>

// MLA bf16-MFMA pipeline R7 (= R6 with flash double-buffered):
// B=2, N=2048, D=1024, L=512, H=16, Dh=64.
// Flash v3: KVBLK=128, QBLK=128, K/V LDS double-buffered with stage(t+1)
// issued before compute(t) -> the compiler's vmcnt(0)+barrier drain lands
// after ~2-3K cycles of compute instead of exposing ~900cy HBM latency per
// tile. One barrier per tile. P buffer is per-wave [16][128] (stride 128)
// with XOR swizzle byte^=(row&7)<<4 (conflict-free b128 reads), reused
// sequentially for the two q-subtiles -> LDS = 32K(K)+32K(V)+16K(P) = 80KiB,
// 2 blocks/CU. s_setprio(1) around MFMA clusters (T5).
// GEMMs / transposes / launch graph unchanged from R6.

typedef __attribute__((ext_vector_type(8))) __bf16 bf16x8;
typedef __attribute__((ext_vector_type(4))) float f32x4;

__device__ inline unsigned short f2bfu(float f) {
    __bf16 b = (__bf16)f;
    return __builtin_bit_cast(unsigned short, b);
}

__device__ inline float exp2_fast(float f) {
    return __builtin_amdgcn_exp2f(f);   // raw v_exp_f32
}

__device__ inline void load_lds16(const void* g, void* l) {
    __builtin_amdgcn_global_load_lds(
        (const __attribute__((address_space(1))) uint32_t*)g,
        (__attribute__((address_space(3))) uint32_t*)l, 16, 0, 0);
}

__device__ inline f32x4 mfma_bf16(bf16x8 a, bf16x8 b, f32x4 c) {
    return __builtin_amdgcn_mfma_f32_16x16x32_bf16(a, b, c, 0, 0, 0);
}

// ---------------- prep kernels ----------------

__global__ __launch_bounds__(256) void cvt_x_kernel(
    const float* __restrict__ src, unsigned short* __restrict__ dst)
{
    int i = (blockIdx.x * 256 + threadIdx.x) * 4;
    float4 v = *(const float4*)&src[i];
    ushort4 o;
    o.x = f2bfu(v.x); o.y = f2bfu(v.y); o.z = f2bfu(v.z); o.w = f2bfu(v.w);
    *(ushort4*)&dst[i] = o;
}

// z-batched: src f32 [R][C] -> dst bf16 [C][R] * scale. grid (C/64, R/64, nz)
__global__ __launch_bounds__(256) void transpose_w2_kernel(
    const float* __restrict__ s0, const float* __restrict__ s1,
    unsigned short* __restrict__ d0, unsigned short* __restrict__ d1,
    int R, int C, float sc0, float sc1)
{
    const float* src = blockIdx.z ? s1 : s0;
    unsigned short* dst = blockIdx.z ? d1 : d0;
    float sc = blockIdx.z ? sc1 : sc0;
    __shared__ float tile[64][65];
    int c0 = blockIdx.x * 64, r0 = blockIdx.y * 64;
    int t = threadIdx.x;
    int col = t & 63, rr = t >> 6;
#pragma unroll
    for (int i = 0; i < 16; ++i)
        tile[rr + i * 4][col] = src[(size_t)(r0 + rr + i * 4) * C + c0 + col];
    __syncthreads();
#pragma unroll
    for (int i = 0; i < 16; ++i) {
        int r2 = rr + i * 4;
        dst[(size_t)(c0 + r2) * R + r0 + col] = f2bfu(tile[col][r2] * sc);
    }
}

// v[b][n][h*64+d] (ld ldv) bf16 -> vt[(b*16+h)*64+d][n]. grid (2048/64, 32)
__global__ __launch_bounds__(256) void transpose_v_kernel(
    const unsigned short* __restrict__ v, int ldv, unsigned short* __restrict__ vt)
{
    __shared__ unsigned short tile[64][65];
    int n0 = blockIdx.x * 64, bh = blockIdx.y;
    int b = bh >> 4, h = bh & 15;
    int t = threadIdx.x;
    int r = t >> 3, c = t & 7;
#pragma unroll
    for (int p = 0; p < 2; ++p) {
        int row = r + p * 32;
        const unsigned short* src = v + (size_t)(b * 2048 + n0 + row) * ldv + h * 64 + c * 8;
        ushort4 a = *(const ushort4*)src;
        ushort4 b4 = *(const ushort4*)(src + 4);
        tile[row][c * 8 + 0] = a.x;  tile[row][c * 8 + 1] = a.y;
        tile[row][c * 8 + 2] = a.z;  tile[row][c * 8 + 3] = a.w;
        tile[row][c * 8 + 4] = b4.x; tile[row][c * 8 + 5] = b4.y;
        tile[row][c * 8 + 6] = b4.z; tile[row][c * 8 + 7] = b4.w;
    }
    __syncthreads();
#pragma unroll
    for (int p = 0; p < 2; ++p) {
        int d = r + p * 32;
        ushort4 o0, o1;
        o0.x = tile[c * 8 + 0][d]; o0.y = tile[c * 8 + 1][d];
        o0.z = tile[c * 8 + 2][d]; o0.w = tile[c * 8 + 3][d];
        o1.x = tile[c * 8 + 4][d]; o1.y = tile[c * 8 + 5][d];
        o1.z = tile[c * 8 + 6][d]; o1.w = tile[c * 8 + 7][d];
        unsigned short* dp = vt + (size_t)(bh * 64 + d) * 2048 + n0 + c * 8;
        *(ushort4*)dp = o0;
        *(ushort4*)(dp + 4) = o1;
    }
}

// ---------------- bf16 MFMA GEMM (m97 structure, z-batched) ----------------
// C[M][N] = A[M][K] @ Bt[N][K]^T (+bias)(relu). 128x128 tile, BK=32.
// grid (N/128, M/128, nz), block 256.
__global__ __launch_bounds__(256) void gemm_bf16_kernel(
    const unsigned short* __restrict__ A0, const unsigned short* __restrict__ A1,
    const unsigned short* __restrict__ B0, const unsigned short* __restrict__ B1,
    void* __restrict__ C0, void* __restrict__ C1,
    int lda, int ldb, int ldc, int K,
    const float* __restrict__ bias, int relu, int out_f32)
{
    const unsigned short* A = blockIdx.z ? A1 : A0;
    const unsigned short* Bt = blockIdx.z ? B1 : B0;
    void* C = blockIdx.z ? C1 : C0;

    __shared__ unsigned short Als[128 * 32];
    __shared__ unsigned short Bls[128 * 32];
    int t = threadIdx.x;
    int lane = t & 63, w = t >> 6;
    int n0 = blockIdx.x * 128, m0 = blockIdx.y * 128;
    int wm = (w & 1) * 64, wn = (w >> 1) * 64;
    int lrow = lane & 15, quad = lane >> 4;

    f32x4 acc[4][4];
    f32x4 z = {0.f, 0.f, 0.f, 0.f};
#pragma unroll
    for (int i = 0; i < 4; ++i)
#pragma unroll
        for (int j = 0; j < 4; ++j) acc[i][j] = z;

    int c0 = t, c1 = t + 256;
    const unsigned short* ag0 = A + (size_t)(m0 + (c0 >> 2)) * lda + (c0 & 3) * 8;
    const unsigned short* ag1 = A + (size_t)(m0 + (c1 >> 2)) * lda + (c1 & 3) * 8;
    const unsigned short* bg0 = Bt + (size_t)(n0 + (c0 >> 2)) * ldb + (c0 & 3) * 8;
    const unsigned short* bg1 = Bt + (size_t)(n0 + (c1 >> 2)) * ldb + (c1 & 3) * 8;

    for (int k0 = 0; k0 < K; k0 += 32) {
        __syncthreads();
        load_lds16(ag0 + k0, &Als[c0 * 8]);
        load_lds16(ag1 + k0, &Als[c1 * 8]);
        load_lds16(bg0 + k0, &Bls[c0 * 8]);
        load_lds16(bg1 + k0, &Bls[c1 * 8]);
        __syncthreads();

        bf16x8 af[4], bfr[4];
#pragma unroll
        for (int mi = 0; mi < 4; ++mi)
            af[mi] = *(const bf16x8*)&Als[(wm + mi * 16 + lrow) * 32 + quad * 8];
#pragma unroll
        for (int ni = 0; ni < 4; ++ni)
            bfr[ni] = *(const bf16x8*)&Bls[(wn + ni * 16 + lrow) * 32 + quad * 8];
#pragma unroll
        for (int mi = 0; mi < 4; ++mi)
#pragma unroll
            for (int ni = 0; ni < 4; ++ni)
                acc[mi][ni] = mfma_bf16(af[mi], bfr[ni], acc[mi][ni]);
    }

#pragma unroll
    for (int mi = 0; mi < 4; ++mi)
#pragma unroll
        for (int ni = 0; ni < 4; ++ni)
#pragma unroll
            for (int r = 0; r < 4; ++r) {
                int row = m0 + wm + mi * 16 + quad * 4 + r;
                int col = n0 + wn + ni * 16 + lrow;
                float v = acc[mi][ni][r];
                if (bias) v += bias[col];
                if (relu) v = fmaxf(v, 0.0f);
                if (out_f32) ((float*)C)[(size_t)row * ldc + col] = v;
                else ((unsigned short*)C)[(size_t)row * ldc + col] = f2bfu(v);
            }
}

// ---------------- MFMA flash attention v3 ----------------
// Q (ldq, scaled by 0.125*log2e), K (ldk): head-interleaved; Vt [32*64][2048].
// grid (2048/128, 32), block 256 (4 waves). Wave w owns Q rows w*32..+31,
// split as 2 q-subtiles of 16 rows. KVBLK=128, K/V LDS double-buffered;
// stage(t+1) issued before compute(t); ONE barrier per tile. Softmax in
// log2 domain with defer-max (THR=8); l lane-partial, reduced in epilogue.
// P: per-wave [16][128] stride-128 with XOR swizzle (row&7)<<4, reused
// sequentially per q-subtile (wave-local).
__global__ __launch_bounds__(256, 2) void flash_mfma_kernel(
    const unsigned short* __restrict__ Q, int ldq,
    const unsigned short* __restrict__ K, int ldk,
    const unsigned short* __restrict__ Vt, unsigned short* __restrict__ O)
{
    __shared__ __align__(16) unsigned short Kls[2][2 * 128 * 32]; // [buf][half d][kv row][32 d] 16KB ea
    __shared__ __align__(16) unsigned short Vls[2][4 * 64 * 32];  // [buf][kv chunk][d row][32 kv] 16KB ea
    __shared__ __align__(16) unsigned short Pls[4][16 * 128];     // per-wave [16][128] swizzled, 4KB ea

    int q0 = blockIdx.x * 128, bh = blockIdx.y;
    int b = bh >> 4, h = bh & 15;
    int t = threadIdx.x;
    int lane = t & 63, w = t >> 6;
    int lrow = lane & 15, quad = lane >> 4;

    // Q fragments: 2 q-subtiles x 2 k-halves (A-layout: row=lrow, k=quad*8)
    bf16x8 qf[2][2];
#pragma unroll
    for (int qb = 0; qb < 2; ++qb) {
        const unsigned short* qrow =
            Q + (size_t)(b * 2048 + q0 + w * 32 + qb * 16 + lrow) * ldq + h * 64;
        qf[qb][0] = *(const bf16x8*)&qrow[quad * 8];
        qf[qb][1] = *(const bf16x8*)&qrow[32 + quad * 8];
    }

    f32x4 z = {0.f, 0.f, 0.f, 0.f};
    f32x4 acco[2][4];
    float m_run[2][4], l_run[2][4];
#pragma unroll
    for (int qb = 0; qb < 2; ++qb)
#pragma unroll
        for (int r = 0; r < 4; ++r) {
            acco[qb][r] = z;
            m_run[qb][r] = -1e30f;
            l_run[qb][r] = 0.f;   // lane-partial sum
        }

    // staging: thread t covers row t>>2 (0..63), segment (t&3)*8
    int row4 = t >> 2;
    int seg = (t & 3) * 8;
    const unsigned short* kg = K + (size_t)(b * 2048 + row4) * ldk + h * 64 + seg;
    const unsigned short* vg = Vt + (size_t)(bh * 64 + row4) * 2048 + seg;

    // P swizzled addresses (bytes): write per (quad,r,kt8), read per (lrow,ks)
    char* pw_base = (char*)&Pls[w][0];

    // prologue: stage tile 0 into buf 0
    {
        load_lds16(kg,                  &Kls[0][t * 8]);
        load_lds16(kg + 64 * ldk,       &Kls[0][t * 8 + 2048]);
        load_lds16(kg + 32,             &Kls[0][4096 + t * 8]);
        load_lds16(kg + 64 * ldk + 32,  &Kls[0][4096 + t * 8 + 2048]);
#pragma unroll
        for (int i = 0; i < 4; ++i)
            load_lds16(vg + i * 32, &Vls[0][i * 2048 + t * 8]);
    }
    __syncthreads();

    int cur = 0;
    for (int kt = 0; kt < 2048; kt += 128) {
        // stage next tile into buf cur^1 (latency hidden under compute below)
        if (kt + 128 < 2048) {
            const unsigned short* kgk = kg + (size_t)(kt + 128) * ldk;
            const unsigned short* vgk = vg + kt + 128;
            int nb = cur ^ 1;
            load_lds16(kgk,                 &Kls[nb][t * 8]);
            load_lds16(kgk + 64 * ldk,      &Kls[nb][t * 8 + 2048]);
            load_lds16(kgk + 32,            &Kls[nb][4096 + t * 8]);
            load_lds16(kgk + 64 * ldk + 32, &Kls[nb][4096 + t * 8 + 2048]);
#pragma unroll
            for (int i = 0; i < 4; ++i)
                load_lds16(vgk + i * 32, &Vls[nb][i * 2048 + t * 8]);
        }

        // S = Q K^T for both q-subtiles; K-frags shared across subtiles
        f32x4 s[2][8];
        __builtin_amdgcn_s_setprio(1);
#pragma unroll
        for (int kt8 = 0; kt8 < 8; ++kt8) {
            bf16x8 k0 = *(const bf16x8*)&Kls[cur][(kt8 * 16 + lrow) * 32 + quad * 8];
            bf16x8 k1 = *(const bf16x8*)&Kls[cur][4096 + (kt8 * 16 + lrow) * 32 + quad * 8];
            s[0][kt8] = mfma_bf16(qf[0][0], k0, z);
            s[0][kt8] = mfma_bf16(qf[0][1], k1, s[0][kt8]);
            s[1][kt8] = mfma_bf16(qf[1][0], k0, z);
            s[1][kt8] = mfma_bf16(qf[1][1], k1, s[1][kt8]);
        }
        __builtin_amdgcn_s_setprio(0);

        // per q-subtile: softmax (log2, defer-max) -> P (swizzled) -> PV
#pragma unroll
        for (int qb = 0; qb < 2; ++qb) {
            float pm[4];
#pragma unroll
            for (int r = 0; r < 4; ++r) {
                float a0 = fmaxf(fmaxf(s[qb][0][r], s[qb][1][r]),
                                 fmaxf(s[qb][2][r], s[qb][3][r]));
                float a1 = fmaxf(fmaxf(s[qb][4][r], s[qb][5][r]),
                                 fmaxf(s[qb][6][r], s[qb][7][r]));
                pm[r] = fmaxf(a0, a1);
            }
            bool ok = (pm[0] <= m_run[qb][0] + 8.f) && (pm[1] <= m_run[qb][1] + 8.f)
                   && (pm[2] <= m_run[qb][2] + 8.f) && (pm[3] <= m_run[qb][3] + 8.f);
            if (!__all(ok)) {
                // rare path: full 16-lane max reduce + rescale
#pragma unroll
                for (int r = 0; r < 4; ++r) {
#pragma unroll
                    for (int off = 1; off < 16; off <<= 1)
                        pm[r] = fmaxf(pm[r], __shfl_xor(pm[r], off, 64));
                    float mnew = fmaxf(m_run[qb][r], pm[r]);
                    float al = exp2_fast(m_run[qb][r] - mnew);
                    m_run[qb][r] = mnew;
                    l_run[qb][r] *= al;
#pragma unroll
                    for (int nt = 0; nt < 4; ++nt) acco[qb][nt][r] *= al;
                }
            }
            // p = exp2(s - m), lane-partial l, P -> bf16 LDS (swizzled, wave-local)
#pragma unroll
            for (int kt8 = 0; kt8 < 8; ++kt8)
#pragma unroll
                for (int r = 0; r < 4; ++r) {
                    float p = exp2_fast(s[qb][kt8][r] - m_run[qb][r]);
                    l_run[qb][r] += p;
                    int row = quad * 4 + r;
                    int boff = (row * 256 + (kt8 * 16 + lrow) * 2) ^ ((row & 7) << 4);
                    *(unsigned short*)(pw_base + boff) = f2bfu(p);
                }
            // PV for this q-subtile
            __builtin_amdgcn_s_setprio(1);
#pragma unroll
            for (int ks = 0; ks < 4; ++ks) {
                int rboff = (lrow * 256 + ks * 64 + quad * 16) ^ ((lrow & 7) << 4);
                bf16x8 pf = *(const bf16x8*)(pw_base + rboff);
#pragma unroll
                for (int nt = 0; nt < 4; ++nt) {
                    bf16x8 vf = *(const bf16x8*)&Vls[cur][ks * 2048 + (nt * 16 + lrow) * 32 + quad * 8];
                    acco[qb][nt] = mfma_bf16(pf, vf, acco[qb][nt]);
                }
            }
            __builtin_amdgcn_s_setprio(0);
        }

        __syncthreads();   // drains stage loads (vmcnt 0) + syncs buffers
        cur ^= 1;
    }

    // epilogue: reduce lane-partial l across the 16-lane row group, write O
#pragma unroll
    for (int qb = 0; qb < 2; ++qb)
#pragma unroll
        for (int r = 0; r < 4; ++r) {
            float lr = l_run[qb][r];
#pragma unroll
            for (int off = 1; off < 16; off <<= 1)
                lr += __shfl_xor(lr, off, 64);
            float rl = 1.0f / lr;
            int row = b * 2048 + q0 + w * 32 + qb * 16 + quad * 4 + r;
#pragma unroll
            for (int nt = 0; nt < 4; ++nt)
                O[(size_t)row * 1024 + h * 64 + nt * 16 + lrow] =
                    f2bfu(acco[qb][nt][r] * rl);
        }
}

// ---------------- launch ----------------

extern "C" void kernel_launch(void* const* d_in, const int* in_sizes, int n_in,
                              void* d_out, int out_size, void* d_ws, size_t ws_size,
                              hipStream_t stream) {
    const float* x   = (const float*)d_in[0];
    const float* Wq  = (const float*)d_in[1];
    const float* Wkv = (const float*)d_in[2];
    const float* Wk1 = (const float*)d_in[3];
    const float* Wk2 = (const float*)d_in[4];
    const float* Wv1 = (const float*)d_in[5];
    const float* Wv2 = (const float*)d_in[6];
    const float* Wo  = (const float*)d_in[7];
    const float* bo  = (const float*)d_in[8];
    float* out = (float*)d_out;

    unsigned short* p = (unsigned short*)d_ws;
    unsigned short* xb    = p; p += 4194304;   // [4096][1024]
    unsigned short* WqkvT = p; p += 3145728;   // [3072][1024]  (Wq^T scaled | Wkv^T)
    unsigned short* WoT   = p; p += 1048576;   // [1024][1024]
    unsigned short* Wk1T  = p; p += 524288;    // [512][1024]
    unsigned short* Wv1T  = p; p += 524288;    // [512][1024]
    unsigned short* Wk2T  = p; p += 524288;    // [1024][512]
    unsigned short* Wv2T  = p; p += 524288;    // [1024][512]
    unsigned short* qkv   = p; p += 12582912;  // [4096][3072]  (q | k-in | v-in)
    unsigned short* tmpb  = p; p += 4194304;   // [4096][1024]  (k1 | v1), reused as attn
    unsigned short* kvo   = p; p += 8388608;   // [4096][2048]  (k | v)
    unsigned short* vtb   = p; p += 4194304;   // [32*64][2048]
    unsigned short* attnb = tmpb;              // alias: tmp dead after k2v2

    dim3 blk(256);
    const float qscale = 0.125f * 1.44269504f;  // Dh^-0.5 * log2(e)

    cvt_x_kernel<<<4096, blk, 0, stream>>>(x, xb);
    transpose_w2_kernel<<<dim3(16, 16, 2), blk, 0, stream>>>(Wq, Wo, WqkvT, WoT, 1024, 1024, qscale, 1.0f);
    transpose_w2_kernel<<<dim3(32, 16, 1), blk, 0, stream>>>(Wkv, Wkv, WqkvT + 1048576, WqkvT + 1048576, 1024, 2048, 1.0f, 1.0f);
    transpose_w2_kernel<<<dim3(8, 16, 2),  blk, 0, stream>>>(Wk1, Wv1, Wk1T, Wv1T, 1024, 512, 1.0f, 1.0f);
    transpose_w2_kernel<<<dim3(16, 8, 2),  blk, 0, stream>>>(Wk2, Wv2, Wk2T, Wv2T, 512, 1024, 1.0f, 1.0f);

    // qkv = x @ [Wq*s | Wkv]   -> qkv [4096][3072]
    gemm_bf16_kernel<<<dim3(24, 32, 1), blk, 0, stream>>>(
        xb, xb, WqkvT, WqkvT, qkv, qkv, 1024, 1024, 3072, 1024, nullptr, 0, 0);
    // k1 = relu(kv_k @ Wk1), v1 = relu(kv_v @ Wv1)  -> tmpb [4096][512|512]
    gemm_bf16_kernel<<<dim3(4, 32, 2), blk, 0, stream>>>(
        qkv + 1024, qkv + 2048, Wk1T, Wv1T, tmpb, tmpb + 512,
        3072, 1024, 1024, 1024, nullptr, 1, 0);
    // k = k1 @ Wk2, v = v1 @ Wv2  -> kvo [4096][1024|1024]   (ldb = 512!)
    gemm_bf16_kernel<<<dim3(8, 32, 2), blk, 0, stream>>>(
        tmpb, tmpb + 512, Wk2T, Wv2T, kvo, kvo + 1024,
        1024, 512, 2048, 512, nullptr, 0, 0);

    transpose_v_kernel<<<dim3(32, 32), blk, 0, stream>>>(kvo + 1024, 2048, vtb);
    flash_mfma_kernel<<<dim3(16, 32), blk, 0, stream>>>(qkv, 3072, kvo, 2048, vtb, attnb);
    // out = attn @ Wo + bo (fp32)
    gemm_bf16_kernel<<<dim3(8, 32, 1), blk, 0, stream>>>(
        attnb, attnb, WoT, WoT, out, out, 1024, 1024, 1024, 1024, bo, 0, 1);
}

// Round 5
// 289.406 us; speedup vs baseline: 1.0635x; 1.0635x over previous
//
#include <hip/hip_runtime.h>
#include <stdint.h>

// MLA bf16-MFMA pipeline R10 (consolidation):
// B=2, N=2048, D=1024, L=512, H=16, Dh=64.
// Flash v2b = R6 structure (KVBLK=128, QBLK=128, 4 waves, V-frags shared
// across both q-subtiles, 2 barriers/tile, defer-max THR=8, lane-partial l)
// + R7-proven P XOR-swizzle: P stride 136->128 halfwords, byte^=(row&7)<<4
// on write and read (conflict-free b128 P-reads, ~2-way writes). LDS 64KB.
// tr-read path (R8/R9) abandoned: deterministic ~1e-2 error, HW semantics
// of ds_read_b64_tr_b16 not matching the derivation; masked-scramble
// signature with near-uniform P.
// GEMM templated on BN; BN=64 for k1v1 and out GEMMs (512 blocks, 2/CU).

typedef __attribute__((ext_vector_type(8))) __bf16 bf16x8;
typedef __attribute__((ext_vector_type(4))) float f32x4;

__device__ inline unsigned short f2bfu(float f) {
    __bf16 b = (__bf16)f;
    return __builtin_bit_cast(unsigned short, b);
}

__device__ inline float exp2_fast(float f) {
    return __builtin_amdgcn_exp2f(f);   // raw v_exp_f32
}

__device__ inline void load_lds16(const void* g, void* l) {
    __builtin_amdgcn_global_load_lds(
        (const __attribute__((address_space(1))) uint32_t*)g,
        (__attribute__((address_space(3))) uint32_t*)l, 16, 0, 0);
}

__device__ inline f32x4 mfma_bf16(bf16x8 a, bf16x8 b, f32x4 c) {
    return __builtin_amdgcn_mfma_f32_16x16x32_bf16(a, b, c, 0, 0, 0);
}

// ---------------- prep kernels ----------------

__global__ __launch_bounds__(256) void cvt_x_kernel(
    const float* __restrict__ src, unsigned short* __restrict__ dst)
{
    int i = (blockIdx.x * 256 + threadIdx.x) * 4;
    float4 v = *(const float4*)&src[i];
    ushort4 o;
    o.x = f2bfu(v.x); o.y = f2bfu(v.y); o.z = f2bfu(v.z); o.w = f2bfu(v.w);
    *(ushort4*)&dst[i] = o;
}

// z-batched: src f32 [R][C] -> dst bf16 [C][R] * scale. grid (C/64, R/64, nz)
__global__ __launch_bounds__(256) void transpose_w2_kernel(
    const float* __restrict__ s0, const float* __restrict__ s1,
    unsigned short* __restrict__ d0, unsigned short* __restrict__ d1,
    int R, int C, float sc0, float sc1)
{
    const float* src = blockIdx.z ? s1 : s0;
    unsigned short* dst = blockIdx.z ? d1 : d0;
    float sc = blockIdx.z ? sc1 : sc0;
    __shared__ float tile[64][65];
    int c0 = blockIdx.x * 64, r0 = blockIdx.y * 64;
    int t = threadIdx.x;
    int col = t & 63, rr = t >> 6;
#pragma unroll
    for (int i = 0; i < 16; ++i)
        tile[rr + i * 4][col] = src[(size_t)(r0 + rr + i * 4) * C + c0 + col];
    __syncthreads();
#pragma unroll
    for (int i = 0; i < 16; ++i) {
        int r2 = rr + i * 4;
        dst[(size_t)(c0 + r2) * R + r0 + col] = f2bfu(tile[col][r2] * sc);
    }
}

// v[b][n][h*64+d] (ld ldv) bf16 -> vt[(b*16+h)*64+d][n]. grid (2048/64, 32)
__global__ __launch_bounds__(256) void transpose_v_kernel(
    const unsigned short* __restrict__ v, int ldv, unsigned short* __restrict__ vt)
{
    __shared__ unsigned short tile[64][65];
    int n0 = blockIdx.x * 64, bh = blockIdx.y;
    int b = bh >> 4, h = bh & 15;
    int t = threadIdx.x;
    int r = t >> 3, c = t & 7;
#pragma unroll
    for (int p = 0; p < 2; ++p) {
        int row = r + p * 32;
        const unsigned short* src = v + (size_t)(b * 2048 + n0 + row) * ldv + h * 64 + c * 8;
        ushort4 a = *(const ushort4*)src;
        ushort4 b4 = *(const ushort4*)(src + 4);
        tile[row][c * 8 + 0] = a.x;  tile[row][c * 8 + 1] = a.y;
        tile[row][c * 8 + 2] = a.z;  tile[row][c * 8 + 3] = a.w;
        tile[row][c * 8 + 4] = b4.x; tile[row][c * 8 + 5] = b4.y;
        tile[row][c * 8 + 6] = b4.z; tile[row][c * 8 + 7] = b4.w;
    }
    __syncthreads();
#pragma unroll
    for (int p = 0; p < 2; ++p) {
        int d = r + p * 32;
        ushort4 o0, o1;
        o0.x = tile[c * 8 + 0][d]; o0.y = tile[c * 8 + 1][d];
        o0.z = tile[c * 8 + 2][d]; o0.w = tile[c * 8 + 3][d];
        o1.x = tile[c * 8 + 4][d]; o1.y = tile[c * 8 + 5][d];
        o1.z = tile[c * 8 + 6][d]; o1.w = tile[c * 8 + 7][d];
        unsigned short* dp = vt + (size_t)(bh * 64 + d) * 2048 + n0 + c * 8;
        *(ushort4*)dp = o0;
        *(ushort4*)(dp + 4) = o1;
    }
}

// ---------------- bf16 MFMA GEMM (m97 structure, z-batched, BN templated) ----
// C[M][N] = A[M][K] @ Bt[N][K]^T (+bias)(relu). 128xBN tile, BK=32.
// grid (N/BN, M/128, nz), block 256.
template<int BN>
__global__ __launch_bounds__(256) void gemm_bf16_kernel(
    const unsigned short* __restrict__ A0, const unsigned short* __restrict__ A1,
    const unsigned short* __restrict__ B0, const unsigned short* __restrict__ B1,
    void* __restrict__ C0, void* __restrict__ C1,
    int lda, int ldb, int ldc, int K,
    const float* __restrict__ bias, int relu, int out_f32)
{
    const unsigned short* A = blockIdx.z ? A1 : A0;
    const unsigned short* Bt = blockIdx.z ? B1 : B0;
    void* C = blockIdx.z ? C1 : C0;

    constexpr int NI = BN / 32;   // N-frags per wave
    __shared__ unsigned short Als[128 * 32];
    __shared__ unsigned short Bls[BN * 32];
    int t = threadIdx.x;
    int lane = t & 63, w = t >> 6;
    int n0 = blockIdx.x * BN, m0 = blockIdx.y * 128;
    int wm = (w & 1) * 64, wn = (w >> 1) * (BN / 2);
    int lrow = lane & 15, quad = lane >> 4;

    f32x4 acc[4][NI];
    f32x4 z = {0.f, 0.f, 0.f, 0.f};
#pragma unroll
    for (int i = 0; i < 4; ++i)
#pragma unroll
        for (int j = 0; j < NI; ++j) acc[i][j] = z;

    int c0 = t, c1 = t + 256;
    const unsigned short* ag0 = A + (size_t)(m0 + (c0 >> 2)) * lda + (c0 & 3) * 8;
    const unsigned short* ag1 = A + (size_t)(m0 + (c1 >> 2)) * lda + (c1 & 3) * 8;
    const unsigned short* bg0 = Bt + (size_t)(n0 + (c0 >> 2)) * ldb + (c0 & 3) * 8;
    const unsigned short* bg1 = Bt + (size_t)(n0 + ((c1 >> 2) & (BN - 1))) * ldb + (c1 & 3) * 8;

    for (int k0 = 0; k0 < K; k0 += 32) {
        __syncthreads();
        load_lds16(ag0 + k0, &Als[c0 * 8]);
        load_lds16(ag1 + k0, &Als[c1 * 8]);
        load_lds16(bg0 + k0, &Bls[c0 * 8]);
        if constexpr (BN == 128) load_lds16(bg1 + k0, &Bls[c1 * 8]);
        __syncthreads();

        bf16x8 af[4], bfr[NI];
#pragma unroll
        for (int mi = 0; mi < 4; ++mi)
            af[mi] = *(const bf16x8*)&Als[(wm + mi * 16 + lrow) * 32 + quad * 8];
#pragma unroll
        for (int ni = 0; ni < NI; ++ni)
            bfr[ni] = *(const bf16x8*)&Bls[(wn + ni * 16 + lrow) * 32 + quad * 8];
#pragma unroll
        for (int mi = 0; mi < 4; ++mi)
#pragma unroll
            for (int ni = 0; ni < NI; ++ni)
                acc[mi][ni] = mfma_bf16(af[mi], bfr[ni], acc[mi][ni]);
    }

#pragma unroll
    for (int mi = 0; mi < 4; ++mi)
#pragma unroll
        for (int ni = 0; ni < NI; ++ni)
#pragma unroll
            for (int r = 0; r < 4; ++r) {
                int row = m0 + wm + mi * 16 + quad * 4 + r;
                int col = n0 + wn + ni * 16 + lrow;
                float v = acc[mi][ni][r];
                if (bias) v += bias[col];
                if (relu) v = fmaxf(v, 0.0f);
                if (out_f32) ((float*)C)[(size_t)row * ldc + col] = v;
                else ((unsigned short*)C)[(size_t)row * ldc + col] = f2bfu(v);
            }
}

// ---------------- MFMA flash attention v2b ----------------
// Q (ldq, scaled by 0.125*log2e), K (ldk): head-interleaved; Vt [32*64][2048].
// grid (2048/128, 32), block 256 (4 waves). Wave w owns Q rows w*32..+31,
// split as 2 q-subtiles of 16 rows. KVBLK=128, single-buffered, 2 barriers.
// Softmax log2-domain, defer-max THR=8, lane-partial l. P per-wave per-qb
// [16][128] halfwords with XOR swizzle byte^=(row&7)<<4 (R7-proven formulas):
// conflict-free b128 reads, ~2-way scalar writes. V-frags shared across qb.
__global__ __launch_bounds__(256, 2) void flash_mfma_kernel(
    const unsigned short* __restrict__ Q, int ldq,
    const unsigned short* __restrict__ K, int ldk,
    const unsigned short* __restrict__ Vt, unsigned short* __restrict__ O)
{
    __shared__ __align__(16) unsigned short Kls[2 * 128 * 32];   // [half d][kv row][32 d] 16KB
    __shared__ __align__(16) unsigned short Vls[4 * 64 * 32];    // [kv chunk][d row][32 kv] 16KB
    __shared__ __align__(16) unsigned short Pls[4][2][16 * 128]; // [wave][qb][16 q][128 kv] swz 32KB

    int q0 = blockIdx.x * 128, bh = blockIdx.y;
    int b = bh >> 4, h = bh & 15;
    int t = threadIdx.x;
    int lane = t & 63, w = t >> 6;
    int lrow = lane & 15, quad = lane >> 4;

    // Q fragments: 2 q-subtiles x 2 k-halves (A-layout: row=lrow, k=quad*8)
    bf16x8 qf[2][2];
#pragma unroll
    for (int qb = 0; qb < 2; ++qb) {
        const unsigned short* qrow =
            Q + (size_t)(b * 2048 + q0 + w * 32 + qb * 16 + lrow) * ldq + h * 64;
        qf[qb][0] = *(const bf16x8*)&qrow[quad * 8];
        qf[qb][1] = *(const bf16x8*)&qrow[32 + quad * 8];
    }

    f32x4 z = {0.f, 0.f, 0.f, 0.f};
    f32x4 acco[2][4];
    float m_run[2][4], l_run[2][4];
#pragma unroll
    for (int qb = 0; qb < 2; ++qb)
#pragma unroll
        for (int r = 0; r < 4; ++r) {
            acco[qb][r] = z;
            m_run[qb][r] = -1e30f;
            l_run[qb][r] = 0.f;   // lane-partial sum
        }

    // staging: thread t covers row t>>2 (0..63), segment (t&3)*8
    int row4 = t >> 2;
    int seg = (t & 3) * 8;
    const unsigned short* kg = K + (size_t)(b * 2048 + row4) * ldk + h * 64 + seg;
    const unsigned short* vg = Vt + (size_t)(bh * 64 + row4) * 2048 + seg;

    char* pb[2] = { (char*)&Pls[w][0][0], (char*)&Pls[w][1][0] };

    for (int kt = 0; kt < 2048; kt += 128) {
        __syncthreads();
        const unsigned short* kgk = kg + (size_t)kt * ldk;
        load_lds16(kgk,                 &Kls[t * 8]);
        load_lds16(kgk + 64 * ldk,      &Kls[t * 8 + 2048]);
        load_lds16(kgk + 32,            &Kls[4096 + t * 8]);
        load_lds16(kgk + 64 * ldk + 32, &Kls[4096 + t * 8 + 2048]);
        const unsigned short* vgk = vg + kt;
#pragma unroll
        for (int i = 0; i < 4; ++i)
            load_lds16(vgk + i * 32, &Vls[i * 2048 + t * 8]);
        __syncthreads();

        // S = Q K^T for both q-subtiles; K-frags shared across subtiles
        f32x4 s[2][8];
        __builtin_amdgcn_s_setprio(1);
#pragma unroll
        for (int kt8 = 0; kt8 < 8; ++kt8) {
            bf16x8 k0 = *(const bf16x8*)&Kls[(kt8 * 16 + lrow) * 32 + quad * 8];
            bf16x8 k1 = *(const bf16x8*)&Kls[4096 + (kt8 * 16 + lrow) * 32 + quad * 8];
            s[0][kt8] = mfma_bf16(qf[0][0], k0, z);
            s[0][kt8] = mfma_bf16(qf[0][1], k1, s[0][kt8]);
            s[1][kt8] = mfma_bf16(qf[1][0], k0, z);
            s[1][kt8] = mfma_bf16(qf[1][1], k1, s[1][kt8]);
        }
        __builtin_amdgcn_s_setprio(0);

        // per q-subtile: softmax (log2, defer-max) -> P (swizzled scalar writes)
#pragma unroll
        for (int qb = 0; qb < 2; ++qb) {
            float pm[4];
#pragma unroll
            for (int r = 0; r < 4; ++r) {
                float a0 = fmaxf(fmaxf(s[qb][0][r], s[qb][1][r]),
                                 fmaxf(s[qb][2][r], s[qb][3][r]));
                float a1 = fmaxf(fmaxf(s[qb][4][r], s[qb][5][r]),
                                 fmaxf(s[qb][6][r], s[qb][7][r]));
                pm[r] = fmaxf(a0, a1);
            }
            bool ok = (pm[0] <= m_run[qb][0] + 8.f) && (pm[1] <= m_run[qb][1] + 8.f)
                   && (pm[2] <= m_run[qb][2] + 8.f) && (pm[3] <= m_run[qb][3] + 8.f);
            if (!__all(ok)) {
                // rare path: full 16-lane max reduce + rescale
#pragma unroll
                for (int r = 0; r < 4; ++r) {
#pragma unroll
                    for (int off = 1; off < 16; off <<= 1)
                        pm[r] = fmaxf(pm[r], __shfl_xor(pm[r], off, 64));
                    float mnew = fmaxf(m_run[qb][r], pm[r]);
                    float al = exp2_fast(m_run[qb][r] - mnew);
                    m_run[qb][r] = mnew;
                    l_run[qb][r] *= al;
#pragma unroll
                    for (int nt = 0; nt < 4; ++nt) acco[qb][nt][r] *= al;
                }
            }
            // p = exp2(s - m), lane-partial l, P -> swizzled LDS (wave-local)
#pragma unroll
            for (int kt8 = 0; kt8 < 8; ++kt8)
#pragma unroll
                for (int r = 0; r < 4; ++r) {
                    float p = exp2_fast(s[qb][kt8][r] - m_run[qb][r]);
                    l_run[qb][r] += p;
                    int row = quad * 4 + r;
                    int boff = (row * 256 + (kt8 * 16 + lrow) * 2) ^ ((row & 7) << 4);
                    *(unsigned short*)(pb[qb] + boff) = f2bfu(p);
                }
        }

        // PV: V-frags shared across both q-subtiles; swizzled b128 P reads
        __builtin_amdgcn_s_setprio(1);
#pragma unroll
        for (int ks = 0; ks < 4; ++ks) {
            int rb = (lrow * 256 + ks * 64 + quad * 16) ^ ((lrow & 7) << 4);
            bf16x8 pf0 = *(const bf16x8*)(pb[0] + rb);
            bf16x8 pf1 = *(const bf16x8*)(pb[1] + rb);
#pragma unroll
            for (int nt = 0; nt < 4; ++nt) {
                bf16x8 vf = *(const bf16x8*)&Vls[ks * 2048 + (nt * 16 + lrow) * 32 + quad * 8];
                acco[0][nt] = mfma_bf16(pf0, vf, acco[0][nt]);
                acco[1][nt] = mfma_bf16(pf1, vf, acco[1][nt]);
            }
        }
        __builtin_amdgcn_s_setprio(0);
    }

    // epilogue: reduce lane-partial l across the 16-lane row group, write O
#pragma unroll
    for (int qb = 0; qb < 2; ++qb)
#pragma unroll
        for (int r = 0; r < 4; ++r) {
            float lr = l_run[qb][r];
#pragma unroll
            for (int off = 1; off < 16; off <<= 1)
                lr += __shfl_xor(lr, off, 64);
            float rl = 1.0f / lr;
            int row = b * 2048 + q0 + w * 32 + qb * 16 + quad * 4 + r;
#pragma unroll
            for (int nt = 0; nt < 4; ++nt)
                O[(size_t)row * 1024 + h * 64 + nt * 16 + lrow] =
                    f2bfu(acco[qb][nt][r] * rl);
        }
}

// ---------------- launch ----------------

extern "C" void kernel_launch(void* const* d_in, const int* in_sizes, int n_in,
                              void* d_out, int out_size, void* d_ws, size_t ws_size,
                              hipStream_t stream) {
    const float* x   = (const float*)d_in[0];
    const float* Wq  = (const float*)d_in[1];
    const float* Wkv = (const float*)d_in[2];
    const float* Wk1 = (const float*)d_in[3];
    const float* Wk2 = (const float*)d_in[4];
    const float* Wv1 = (const float*)d_in[5];
    const float* Wv2 = (const float*)d_in[6];
    const float* Wo  = (const float*)d_in[7];
    const float* bo  = (const float*)d_in[8];
    float* out = (float*)d_out;

    unsigned short* p = (unsigned short*)d_ws;
    unsigned short* xb    = p; p += 4194304;   // [4096][1024]
    unsigned short* WqkvT = p; p += 3145728;   // [3072][1024]  (Wq^T scaled | Wkv^T)
    unsigned short* WoT   = p; p += 1048576;   // [1024][1024]
    unsigned short* Wk1T  = p; p += 524288;    // [512][1024]
    unsigned short* Wv1T  = p; p += 524288;    // [512][1024]
    unsigned short* Wk2T  = p; p += 524288;    // [1024][512]
    unsigned short* Wv2T  = p; p += 524288;    // [1024][512]
    unsigned short* qkv   = p; p += 12582912;  // [4096][3072]  (q | k-in | v-in)
    unsigned short* tmpb  = p; p += 4194304;   // [4096][1024]  (k1 | v1), reused as attn
    unsigned short* kvo   = p; p += 8388608;   // [4096][2048]  (k | v)
    unsigned short* vtb   = p; p += 4194304;   // [32*64][2048]
    unsigned short* attnb = tmpb;              // alias: tmp dead after k2v2

    dim3 blk(256);
    const float qscale = 0.125f * 1.44269504f;  // Dh^-0.5 * log2(e)

    cvt_x_kernel<<<4096, blk, 0, stream>>>(x, xb);
    transpose_w2_kernel<<<dim3(16, 16, 2), blk, 0, stream>>>(Wq, Wo, WqkvT, WoT, 1024, 1024, qscale, 1.0f);
    transpose_w2_kernel<<<dim3(32, 16, 1), blk, 0, stream>>>(Wkv, Wkv, WqkvT + 1048576, WqkvT + 1048576, 1024, 2048, 1.0f, 1.0f);
    transpose_w2_kernel<<<dim3(8, 16, 2),  blk, 0, stream>>>(Wk1, Wv1, Wk1T, Wv1T, 1024, 512, 1.0f, 1.0f);
    transpose_w2_kernel<<<dim3(16, 8, 2),  blk, 0, stream>>>(Wk2, Wv2, Wk2T, Wv2T, 512, 1024, 1.0f, 1.0f);

    // qkv = x @ [Wq*s | Wkv]   -> qkv [4096][3072]
    gemm_bf16_kernel<128><<<dim3(24, 32, 1), blk, 0, stream>>>(
        xb, xb, WqkvT, WqkvT, qkv, qkv, 1024, 1024, 3072, 1024, nullptr, 0, 0);
    // k1 = relu(kv_k @ Wk1), v1 = relu(kv_v @ Wv1)  -> tmpb [4096][512|512]
    // BN=64: 512 blocks (2/CU) instead of 256 (1/CU)
    gemm_bf16_kernel<64><<<dim3(8, 32, 2), blk, 0, stream>>>(
        qkv + 1024, qkv + 2048, Wk1T, Wv1T, tmpb, tmpb + 512,
        3072, 1024, 1024, 1024, nullptr, 1, 0);
    // k = k1 @ Wk2, v = v1 @ Wv2  -> kvo [4096][1024|1024]   (ldb = 512!)
    gemm_bf16_kernel<128><<<dim3(8, 32, 2), blk, 0, stream>>>(
        tmpb, tmpb + 512, Wk2T, Wv2T, kvo, kvo + 1024,
        1024, 512, 2048, 512, nullptr, 0, 0);

    transpose_v_kernel<<<dim3(32, 32), blk, 0, stream>>>(kvo + 1024, 2048, vtb);
    flash_mfma_kernel<<<dim3(16, 32), blk, 0, stream>>>(qkv, 3072, kvo, 2048, vtb, attnb);
    // out = attn @ Wo + bo (fp32), BN=64 for occupancy
    gemm_bf16_kernel<64><<<dim3(16, 32, 1), blk, 0, stream>>>(
        attnb, attnb, WoT, WoT, out, out, 1024, 1024, 1024, 1024, bo, 0, 1);
}